// Round 4
// baseline (264.885 us; speedup 1.0000x reference)
//
#include <hip/hip_runtime.h>
#include <cstdint>
#include <cstddef>

#define DEV __device__ __forceinline__

typedef float v2f __attribute__((ext_vector_type(2)));

DEV float fsig(float x)  { return __builtin_amdgcn_rcpf(1.0f + __expf(-x)); }
DEV float ftanh_(float x){ return 1.0f - 2.0f * __builtin_amdgcn_rcpf(1.0f + __expf(2.0f * x)); }
DEV float readlanef(float v, int l) {
    return __uint_as_float(__builtin_amdgcn_readlane(__float_as_uint(v), l));
}
DEV v2f fma2v(v2f a, float b, v2f c) {
    return (v2f){ fmaf(a.x, b, c.x), fmaf(a.y, b, c.y) };
}

// ---------------- ws layout (float offsets) ----------------
constexpr size_t ACC   = 0;                 // 64  (2 tracks x (16 sum + 16 sumsq))
constexpr size_t LO    = 128;               // 65536  Lo[64][128][8]
constexpr size_t RO    = LO + 65536;        // 65536  Ro[64][128][8]
constexpr size_t HBUF  = RO + 65536;        // 262144 h[track][8192][16]
constexpr size_t XW0   = HBUF + 262144;     // 393216 xw0[8192][48]
constexpr size_t ZLAST = XW0 + 393216;      // 1024   zlast[64][16]

// ===== K1: gate GRU, 1 seq/wave, skewed layers, readlane broadcast =====
// 128 blocks x 64 thr. j=tid&7, layer=(tid>>3)&1; lanes 0-15 hold state.
// Layer-0 input transform (xwg = bih0 + Wih0.x) precomputed in staging phase;
// recurrence loop is VALU/SALU only (readlane broadcast, LDS prefetch off-chain).
__global__ __launch_bounds__(64) void k1_gate(
    const float* __restrict__ Local, const float* __restrict__ Remote,
    const float* __restrict__ Wih0, const float* __restrict__ Whh0,
    const float* __restrict__ bih0, const float* __restrict__ bhh0,
    const float* __restrict__ Wih1, const float* __restrict__ Whh1,
    const float* __restrict__ bih1, const float* __restrict__ bhh1,
    float* __restrict__ ws)
{
    const int tid = threadIdx.x;
    const int j = tid & 7;
    const int layer = (tid >> 3) & 1;
    const int blk = blockIdx.x;
    const int track = blk >> 6;
    const int b = blk & 63;
    if (blk == 0) ws[ACC + tid] = 0.f;

    __shared__ float xwg[128][24];     // precomputed bih0 + Wih0 . x(t)
    __shared__ float h1all[128][9];

    const float* __restrict__ src = track ? Remote : Local;
    for (int t = tid; t < 128; t += 64) {
        const float* p = src + ((size_t)b * 128 + t) * 132 + 128;
        float x0 = p[0], x1 = p[1], x2 = p[2];
#pragma unroll
        for (int u = 0; u < 24; ++u) {
            float a = bih0[u];
            a = fmaf(Wih0[u * 3 + 0], x0, a);
            a = fmaf(Wih0[u * 3 + 1], x1, a);
            a = fmaf(Wih0[u * 3 + 2], x2, a);
            xwg[t][u] = a;
        }
    }

    v2f wrz[16], wnn[16];
    float base_r, base_z, base_in, base_dn;
    if (layer == 0) {
#pragma unroll
        for (int k = 0; k < 8; ++k) {
            wrz[k] = (v2f){ Whh0[j * 8 + k], Whh0[(8 + j) * 8 + k] };
            wnn[k] = (v2f){ 0.f, Whh0[(16 + j) * 8 + k] };
            wrz[8 + k] = (v2f){0.f, 0.f};
            wnn[8 + k] = (v2f){0.f, 0.f};
        }
        base_r = bhh0[j];
        base_z = bhh0[8 + j];
        base_in = 0.f;                 // xwg carries bih0
        base_dn = bhh0[16 + j];
    } else {
#pragma unroll
        for (int k = 0; k < 8; ++k) {
            wrz[k] = (v2f){ Wih1[j * 8 + k], Wih1[(8 + j) * 8 + k] };
            wnn[k] = (v2f){ Wih1[(16 + j) * 8 + k], 0.f };
            wrz[8 + k] = (v2f){ Whh1[j * 8 + k], Whh1[(8 + j) * 8 + k] };
            wnn[8 + k] = (v2f){ 0.f, Whh1[(16 + j) * 8 + k] };
        }
        base_r = bih1[j] + bhh1[j];
        base_z = bih1[8 + j] + bhh1[8 + j];
        base_in = bih1[16 + j];
        base_dn = bhh1[16 + j];
    }
    const float m0f = (layer == 0) ? 1.f : 0.f;
    __syncthreads();   // once: xwg staged

    float hown = 0.f;
    float p0 = xwg[0][j], p1 = xwg[0][8 + j], p2 = xwg[0][16 + j];
#pragma unroll 1
    for (int t = 0; t <= 128; ++t) {
        int tn = t < 127 ? t + 1 : 127;
        float q0 = xwg[tn][j], q1 = xwg[tn][8 + j], q2 = xwg[tn][16 + j];
        float vb[16];
#pragma unroll
        for (int k = 0; k < 16; ++k) vb[k] = readlanef(hown, k);
        v2f arz = (v2f){ fmaf(m0f, p0, base_r), fmaf(m0f, p1, base_z) };
        v2f ann = (v2f){ fmaf(m0f, p2, base_in), base_dn };
#pragma unroll
        for (int k = 0; k < 16; ++k) {
            arz = fma2v(wrz[k], vb[k], arz);
            ann = fma2v(wnn[k], vb[k], ann);
        }
        float r = fsig(arz.x);
        float z = fsig(arz.y);
        float n = ftanh_(ann.x + r * ann.y);
        float hnew = (1.f - z) * n + z * hown;
        bool act = layer ? (t >= 1) : (t < 128);
        hown = act ? hnew : hown;
        if (tid >= 8 && tid < 16 && t >= 1) h1all[t - 1][j] = hown;
        p0 = q0; p1 = q1; p2 = q2;
    }
    __syncthreads();

    // softmax over layer-1 outputs
    float* __restrict__ outp = ws + (track ? RO : LO);
    for (int t = tid; t < 128; t += 64) {
        float vv[8];
#pragma unroll
        for (int k = 0; k < 8; ++k) vv[k] = h1all[t][k];
        float mx = vv[0];
#pragma unroll
        for (int k = 1; k < 8; ++k) mx = fmaxf(mx, vv[k]);
        float ssum = 0.f;
#pragma unroll
        for (int k = 0; k < 8; ++k) { vv[k] = __expf(vv[k] - mx); ssum += vv[k]; }
        float inv = __builtin_amdgcn_rcpf(ssum);
        size_t base = ((size_t)b * 128 + t) * 8;
        float4 o0 = make_float4(vv[0] * inv, vv[1] * inv, vv[2] * inv, vv[3] * inv);
        float4 o1 = make_float4(vv[4] * inv, vv[5] * inv, vv[6] * inv, vv[7] * inv);
        *(float4*)(outp + base) = o0;
        *(float4*)(outp + base + 4) = o1;
    }
}

// ====== K2: expert layer-1 GEMM + gate mix + batch-stat accumulation ======
// Coalesced w1 staging (read-linear, LDS transpose), full-K in LDS, one barrier.
__global__ __launch_bounds__(256) void k2_expert1(
    const float* __restrict__ Local, const float* __restrict__ Remote,
    const float* __restrict__ ae_w1, const float* __restrict__ ae_b1,
    float* __restrict__ ws)
{
    const int blk = blockIdx.x;
    const int track = blk >> 7;
    const int n0 = (blk & 127) * 64;
    const float* __restrict__ X = track ? Remote : Local;
    const float* __restrict__ om = ws + (track ? RO : LO);

    __shared__ __align__(16) float xsh[64 * 132];     // row stride 132
    __shared__ __align__(16) float wsh[16 * 1040];    // [h][e][130]
    __shared__ float omsh[64][8];
    __shared__ float b1sh[128];
    __shared__ float red[32];
    const int tid = threadIdx.x;

    // X rows: 128 contiguous floats each, float4-coalesced
    for (int i = tid; i < 2048; i += 256) {
        int r = i >> 5, q = i & 31;
        ((float4*)&xsh[r * 132])[q] = ((const float4*)(X + (size_t)(n0 + r) * 132))[q];
    }
    // w1: linear coalesced read, transposed LDS write. i=((e*128+kk)*16+h)
    for (int i4 = tid; i4 < 4096; i4 += 256) {
        float4 v = ((const float4*)ae_w1)[i4];
        int i = i4 * 4;
#pragma unroll
        for (int c = 0; c < 4; ++c) {
            int ii = i + c;
            int h = ii & 15, kk = (ii >> 4) & 127, e = ii >> 11;
            float vc = c == 0 ? v.x : c == 1 ? v.y : c == 2 ? v.z : v.w;
            wsh[h * 1040 + e * 130 + kk] = vc;
        }
    }
    for (int i = tid; i < 512; i += 256) omsh[i >> 3][i & 7] = om[(size_t)(n0 + (i >> 3)) * 8 + (i & 7)];
    for (int i = tid; i < 128; i += 256) b1sh[i] = ae_b1[i];
    if (tid < 32) red[tid] = 0.f;
    __syncthreads();

    const int hh = tid & 15, rg = tid >> 4;
    float acc[4][8];
#pragma unroll
    for (int r = 0; r < 4; ++r)
#pragma unroll
        for (int e = 0; e < 8; ++e) acc[r][e] = 0.f;

#pragma unroll 4
    for (int kq = 0; kq < 32; ++kq) {
        float4 xv[4], wv[8];
#pragma unroll
        for (int r = 0; r < 4; ++r) xv[r] = *(const float4*)&xsh[(rg * 4 + r) * 132 + kq * 4];
#pragma unroll
        for (int e = 0; e < 8; ++e) wv[e] = *(const float4*)&wsh[hh * 1040 + e * 130 + kq * 4];
#pragma unroll
        for (int r = 0; r < 4; ++r)
#pragma unroll
            for (int e = 0; e < 8; ++e) {
                float a = acc[r][e];
                a = fmaf(xv[r].x, wv[e].x, a);
                a = fmaf(xv[r].y, wv[e].y, a);
                a = fmaf(xv[r].z, wv[e].z, a);
                a = fmaf(xv[r].w, wv[e].w, a);
                acc[r][e] = a;
            }
    }

    float s = 0.f, s2 = 0.f;
    float* __restrict__ hout = ws + HBUF + (size_t)track * 131072;
#pragma unroll
    for (int r = 0; r < 4; ++r) {
        int row = rg * 4 + r;
        float hv = 0.f;
#pragma unroll
        for (int e = 0; e < 8; ++e) hv = fmaf(omsh[row][e], acc[r][e] + b1sh[e * 16 + hh], hv);
        hout[(size_t)(n0 + row) * 16 + hh] = hv;
        s += hv; s2 += hv * hv;
    }
    __syncthreads();
    atomicAdd(&red[hh], s);
    atomicAdd(&red[16 + hh], s2);
    __syncthreads();
    if (tid < 32) atomicAdd(&ws[ACC + track * 32 + tid], red[tid]);
}

// ====== K3: BN finalize + ELU + expert layer-2 + Z=ZL+ZR + xw0 precompute ======
__global__ __launch_bounds__(256) void k3_bn_mlp2(
    const float* __restrict__ ae_w2, const float* __restrict__ ae_b2,
    const float* __restrict__ ae_g, const float* __restrict__ ae_bt,
    const float* __restrict__ mWih0, const float* __restrict__ mbih0,
    float* __restrict__ ws)
{
    const int n0 = blockIdx.x * 64;
    const int tid = threadIdx.x;
    __shared__ float actsh[2][64][16];
    __shared__ float omsh[2][64][8];
    __shared__ float w2sh[2048];
    __shared__ float b2sh[128];
    __shared__ float zsh[64][17];
    __shared__ float wihsh[48][17];
    __shared__ float bihsh[48];
    __shared__ float stat[4][16];

    if (tid < 32) {
        int trk = tid >> 4, h = tid & 15;
        float s = ws[ACC + trk * 32 + h], s2 = ws[ACC + trk * 32 + 16 + h];
        float m = s * (1.f / 8192.f);
        float v = fmaxf(s2 * (1.f / 8192.f) - m * m, 0.f);
        stat[trk * 2][h] = m;
        stat[trk * 2 + 1][h] = rsqrtf(v + 1e-5f);
    }
    for (int i = tid; i < 2048; i += 256) w2sh[i] = ae_w2[i];
    for (int i = tid; i < 128; i += 256) b2sh[i] = ae_b2[i];
    for (int i = tid; i < 768; i += 256) wihsh[i >> 4][i & 15] = mWih0[i];
    if (tid < 48) bihsh[tid] = mbih0[tid];
    for (int i = tid; i < 1024; i += 256) {
        int trk = i >> 9, r = (i >> 3) & 63, e = i & 7;
        omsh[trk][r][e] = ws[(trk ? RO : LO) + (size_t)(n0 + r) * 8 + e];
    }
    __syncthreads();

    for (int i = tid; i < 2048; i += 256) {
        int trk = i >> 10, r = (i >> 4) & 63, h = i & 15;
        float v = ws[HBUF + (size_t)trk * 131072 + (size_t)(n0 + r) * 16 + h];
        float a = ae_g[h] * (v - stat[trk * 2][h]) * stat[trk * 2 + 1][h] + ae_bt[h];
        actsh[trk][r][h] = a > 0.f ? a : expm1f(a);
    }
    __syncthreads();

    for (int i = tid; i < 1024; i += 256) {
        int r = i >> 4, o = i & 15;
        float accv = 0.f;
#pragma unroll
        for (int trk = 0; trk < 2; ++trk) {
#pragma unroll
            for (int e = 0; e < 8; ++e) {
                const float* w = &w2sh[e * 256 + o];
                float t = b2sh[e * 16 + o];
#pragma unroll
                for (int h = 0; h < 16; ++h) t = fmaf(actsh[trk][r][h], w[h * 16], t);
                accv = fmaf(omsh[trk][r][e], t, accv);
            }
        }
        zsh[r][o] = accv;
    }
    __syncthreads();

    // xw0[n][48] = bih0 + Wih0 . Z[n]
    for (int i = tid; i < 3072; i += 256) {
        int r = i / 48, gr = i - r * 48;
        float a = bihsh[gr];
#pragma unroll
        for (int k = 0; k < 16; ++k) a = fmaf(zsh[r][k], wihsh[gr][k], a);
        ws[XW0 + (size_t)(n0 + r) * 48 + gr] = a;
    }
}

// ===== K4: main GRU, 1 seq/wave, skewed layers, readlane broadcast =====
// 64 blocks x 64 thr. j=tid&15, layer=(tid>>4)&1; lanes 0-31 hold state
// (h0 in 0-15, h1 in 16-31). 32-slot readlane broadcast, zero-padded weights,
// uniform instruction stream; no DS ops on the critical chain.
__global__ __launch_bounds__(64) void k4_maingru(
    const float* __restrict__ Whh0, const float* __restrict__ bhh0,
    const float* __restrict__ Wih1, const float* __restrict__ Whh1,
    const float* __restrict__ bih1, const float* __restrict__ bhh1,
    float* __restrict__ ws)
{
    const int tid = threadIdx.x;
    const int j = tid & 15;
    const int layer = (tid >> 4) & 1;
    const int seq = blockIdx.x;

    __shared__ __align__(16) float4 xw4[1536];   // xw0[128][48] staged
    float* xwsh = (float*)xw4;

    const float4* __restrict__ xsrc = (const float4*)(ws + XW0 + (size_t)seq * 6144);
    for (int i = tid; i < 1536; i += 64) xw4[i] = xsrc[i];

    v2f wrz[32], wnn[32];
    float base_r, base_z, base_in, base_dn;
    if (layer == 0) {
#pragma unroll
        for (int k = 0; k < 16; ++k) {
            wrz[k] = (v2f){ Whh0[j * 16 + k], Whh0[(16 + j) * 16 + k] };
            wnn[k] = (v2f){ 0.f, Whh0[(32 + j) * 16 + k] };
            wrz[16 + k] = (v2f){0.f, 0.f};
            wnn[16 + k] = (v2f){0.f, 0.f};
        }
        base_r = bhh0[j];
        base_z = bhh0[16 + j];
        base_in = 0.f;                       // xw0 carries bih0 + Wih0.z
        base_dn = bhh0[32 + j];
    } else {
#pragma unroll
        for (int k = 0; k < 16; ++k) {
            wrz[k] = (v2f){ Wih1[j * 16 + k], Wih1[(16 + j) * 16 + k] };
            wnn[k] = (v2f){ Wih1[(32 + j) * 16 + k], 0.f };
            wrz[16 + k] = (v2f){ Whh1[j * 16 + k], Whh1[(16 + j) * 16 + k] };
            wnn[16 + k] = (v2f){ 0.f, Whh1[(32 + j) * 16 + k] };
        }
        base_r = bih1[j] + bhh1[j];
        base_z = bih1[16 + j] + bhh1[16 + j];
        base_in = bih1[32 + j];
        base_dn = bhh1[32 + j];
    }
    const float m0f = (layer == 0) ? 1.f : 0.f;
    __syncthreads();   // once: xw0 staged

    float hown = 0.f;
    float p0 = xwsh[j], p1 = xwsh[16 + j], p2 = xwsh[32 + j];
#pragma unroll 1
    for (int t = 0; t <= 128; ++t) {
        int tn = (t < 127 ? t + 1 : 127) * 48;
        float q0 = xwsh[tn + j], q1 = xwsh[tn + 16 + j], q2 = xwsh[tn + 32 + j];
        float vb[32];
#pragma unroll
        for (int k = 0; k < 32; ++k) vb[k] = readlanef(hown, k);
        v2f arz = (v2f){ fmaf(m0f, p0, base_r), fmaf(m0f, p1, base_z) };
        v2f ann = (v2f){ fmaf(m0f, p2, base_in), base_dn };
#pragma unroll
        for (int k = 0; k < 32; ++k) {
            arz = fma2v(wrz[k], vb[k], arz);
            ann = fma2v(wnn[k], vb[k], ann);
        }
        float r = fsig(arz.x);
        float z = fsig(arz.y);
        float n = ftanh_(ann.x + r * ann.y);
        float hnew = (1.f - z) * n + z * hown;
        bool act = layer ? (t >= 1) : (t < 128);
        hown = act ? hnew : hown;
        p0 = q0; p1 = q1; p2 = q2;
    }
    if (tid >= 16 && tid < 32) ws[ZLAST + (size_t)seq * 16 + j] = hown;
}

// ===== K5: decoder MLP fused (layer1+BN redundant per block, layer2 slice) =====
__global__ __launch_bounds__(256) void k5_dec(
    const float* __restrict__ Remote,
    const float* __restrict__ md_w1, const float* __restrict__ md_b1,
    const float* __restrict__ md_g, const float* __restrict__ md_bt,
    const float* __restrict__ md_w2, const float* __restrict__ md_b2,
    const float* __restrict__ ws, float* __restrict__ out)
{
    const int o0 = blockIdx.x * 8;
    const int tid = threadIdx.x;
    __shared__ float xsh[64][17];
    __shared__ float omsh[64][8];
    __shared__ float w1sh[2176];
    __shared__ float b1sh[128];
    __shared__ float hsh[64][17];
    __shared__ float ssum[16], ss2[16], mstat[2][16];
    __shared__ float ash[64][17];
    __shared__ float w2sh[8][16][8];
    __shared__ float b2sh[8][8];

    for (int i = tid; i < 1024; i += 256) xsh[i >> 4][i & 15] = ws[ZLAST + i];
    if (tid < 64) xsh[tid][16] = Remote[((size_t)tid * 128 + 127) * 132 + 131];
    for (int i = tid; i < 512; i += 256)
        omsh[i >> 3][i & 7] = ws[RO + ((size_t)(i >> 3) * 128 + 127) * 8 + (i & 7)];
    for (int i = tid; i < 2176; i += 256) w1sh[i] = md_w1[i];
    for (int i = tid; i < 128; i += 256) b1sh[i] = md_b1[i];
    for (int i = tid; i < 1024; i += 256) {
        int e = i >> 7, h = (i >> 3) & 15, oo = i & 7;
        w2sh[e][h][oo] = md_w2[((size_t)e * 16 + h) * 128 + o0 + oo];
    }
    if (tid < 64) b2sh[tid >> 3][tid & 7] = md_b2[(size_t)(tid >> 3) * 128 + o0 + (tid & 7)];
    if (tid < 16) { ssum[tid] = 0.f; ss2[tid] = 0.f; }
    __syncthreads();

    for (int i = tid; i < 1024; i += 256) {
        int b = i >> 4, h = i & 15;
        float accv = 0.f;
#pragma unroll
        for (int e = 0; e < 8; ++e) {
            float t = b1sh[e * 16 + h];
            const float* w = &w1sh[e * 272 + h];
#pragma unroll
            for (int i2 = 0; i2 < 17; ++i2) t = fmaf(xsh[b][i2], w[i2 * 16], t);
            accv = fmaf(omsh[b][e], t, accv);
        }
        hsh[b][h] = accv;
        atomicAdd(&ssum[h], accv);
        atomicAdd(&ss2[h], accv * accv);
    }
    __syncthreads();
    if (tid < 16) {
        float m = ssum[tid] * (1.f / 64.f);
        float v = fmaxf(ss2[tid] * (1.f / 64.f) - m * m, 0.f);
        mstat[0][tid] = m;
        mstat[1][tid] = rsqrtf(v + 1e-5f);
    }
    __syncthreads();
    for (int i = tid; i < 1024; i += 256) {
        int b = i >> 4, h = i & 15;
        float a = md_g[h] * (hsh[b][h] - mstat[0][h]) * mstat[1][h] + md_bt[h];
        ash[b][h] = a > 0.f ? a : expm1f(a);
    }
    __syncthreads();

    for (int i = tid; i < 512; i += 256) {
        int b = i >> 3, oo = i & 7;
        float accv = 0.f;
#pragma unroll
        for (int e = 0; e < 8; ++e) {
            float t = b2sh[e][oo];
#pragma unroll
            for (int h = 0; h < 16; ++h) t = fmaf(ash[b][h], w2sh[e][h][oo], t);
            accv = fmaf(omsh[b][e], t, accv);
        }
        out[(size_t)b * 128 + o0 + oo] = accv;
    }
}

extern "C" void kernel_launch(void* const* d_in, const int* in_sizes, int n_in,
                              void* d_out, int out_size, void* d_ws, size_t ws_size,
                              hipStream_t stream) {
    const float* Local  = (const float*)d_in[0];
    const float* Remote = (const float*)d_in[1];
    const float* gWih0  = (const float*)d_in[2];
    const float* gWhh0  = (const float*)d_in[3];
    const float* gbih0  = (const float*)d_in[4];
    const float* gbhh0  = (const float*)d_in[5];
    const float* gWih1  = (const float*)d_in[6];
    const float* gWhh1  = (const float*)d_in[7];
    const float* gbih1  = (const float*)d_in[8];
    const float* gbhh1  = (const float*)d_in[9];
    const float* mWih0  = (const float*)d_in[10];
    const float* mWhh0  = (const float*)d_in[11];
    const float* mbih0  = (const float*)d_in[12];
    const float* mbhh0  = (const float*)d_in[13];
    const float* mWih1  = (const float*)d_in[14];
    const float* mWhh1  = (const float*)d_in[15];
    const float* mbih1  = (const float*)d_in[16];
    const float* mbhh1  = (const float*)d_in[17];
    const float* ae_w1  = (const float*)d_in[18];
    const float* ae_b1  = (const float*)d_in[19];
    const float* ae_w2  = (const float*)d_in[20];
    const float* ae_b2  = (const float*)d_in[21];
    const float* ae_g   = (const float*)d_in[22];
    const float* ae_bt  = (const float*)d_in[23];
    const float* md_w1  = (const float*)d_in[24];
    const float* md_b1  = (const float*)d_in[25];
    const float* md_w2  = (const float*)d_in[26];
    const float* md_b2  = (const float*)d_in[27];
    const float* md_g   = (const float*)d_in[28];
    const float* md_bt  = (const float*)d_in[29];
    float* ws  = (float*)d_ws;
    float* out = (float*)d_out;

    k1_gate<<<128, 64, 0, stream>>>(Local, Remote, gWih0, gWhh0, gbih0, gbhh0,
                                    gWih1, gWhh1, gbih1, gbhh1, ws);
    k2_expert1<<<256, 256, 0, stream>>>(Local, Remote, ae_w1, ae_b1, ws);
    k3_bn_mlp2<<<128, 256, 0, stream>>>(ae_w2, ae_b2, ae_g, ae_bt, mWih0, mbih0, ws);
    k4_maingru<<<64, 64, 0, stream>>>(mWhh0, mbhh0, mWih1, mWhh1, mbih1, mbhh1, ws);
    k5_dec<<<16, 256, 0, stream>>>(Remote, md_w1, md_b1, md_g, md_bt,
                                   md_w2, md_b2, ws, out);
}

// Round 5
// 247.847 us; speedup vs baseline: 1.0687x; 1.0687x over previous
//
#include <hip/hip_runtime.h>
#include <cstdint>
#include <cstddef>

#define DEV __device__ __forceinline__

typedef float v2f __attribute__((ext_vector_type(2)));

DEV float fsig(float x)  { return __builtin_amdgcn_rcpf(1.0f + __expf(-x)); }
DEV float ftanh_(float x){ return 1.0f - 2.0f * __builtin_amdgcn_rcpf(1.0f + __expf(2.0f * x)); }
DEV float readlanef(float v, int l) {
    return __uint_as_float(__builtin_amdgcn_readlane(__float_as_uint(v), l));
}
DEV v2f fma2v(v2f a, float b, v2f c) {
    return (v2f){ fmaf(a.x, b, c.x), fmaf(a.y, b, c.y) };
}

// ---------------- ws layout (float offsets) ----------------
constexpr size_t ACC   = 0;                 // 64  (2 tracks x (16 sum + 16 sumsq))
constexpr size_t LO    = 128;               // 65536  Lo[64][128][8]
constexpr size_t RO    = LO + 65536;        // 65536  Ro[64][128][8]
constexpr size_t HBUF  = RO + 65536;        // 262144 h[track][8192][16]
constexpr size_t XW0   = HBUF + 262144;     // 393216 xw0[8192][48]
constexpr size_t ZLAST = XW0 + 393216;      // 1024   zlast[64][16]

// ===== K1: gate GRU, 1 seq/wave, skewed layers, readlane broadcast =====
// launch_bounds(64,1): single wave per EU -> no VGPR cap -> no weight spills.
__global__ __launch_bounds__(64, 1) void k1_gate(
    const float* __restrict__ Local, const float* __restrict__ Remote,
    const float* __restrict__ Wih0, const float* __restrict__ Whh0,
    const float* __restrict__ bih0, const float* __restrict__ bhh0,
    const float* __restrict__ Wih1, const float* __restrict__ Whh1,
    const float* __restrict__ bih1, const float* __restrict__ bhh1,
    float* __restrict__ ws)
{
    const int tid = threadIdx.x;
    const int j = tid & 7;
    const int layer = (tid >> 3) & 1;
    const int blk = blockIdx.x;
    const int track = blk >> 6;
    const int b = blk & 63;
    if (blk == 0) ws[ACC + tid] = 0.f;

    __shared__ float xwg[128][24];     // precomputed bih0 + Wih0 . x(t)
    __shared__ float h1all[128][9];

    const float* __restrict__ src = track ? Remote : Local;
    for (int t = tid; t < 128; t += 64) {
        const float* p = src + ((size_t)b * 128 + t) * 132 + 128;
        float x0 = p[0], x1 = p[1], x2 = p[2];
#pragma unroll
        for (int u = 0; u < 24; ++u) {
            float a = bih0[u];
            a = fmaf(Wih0[u * 3 + 0], x0, a);
            a = fmaf(Wih0[u * 3 + 1], x1, a);
            a = fmaf(Wih0[u * 3 + 2], x2, a);
            xwg[t][u] = a;
        }
    }

    v2f wrz[16], wnn[16];
    float base_r, base_z, base_in, base_dn;
    if (layer == 0) {
#pragma unroll
        for (int k = 0; k < 8; ++k) {
            wrz[k] = (v2f){ Whh0[j * 8 + k], Whh0[(8 + j) * 8 + k] };
            wnn[k] = (v2f){ 0.f, Whh0[(16 + j) * 8 + k] };
            wrz[8 + k] = (v2f){0.f, 0.f};
            wnn[8 + k] = (v2f){0.f, 0.f};
        }
        base_r = bhh0[j];
        base_z = bhh0[8 + j];
        base_in = 0.f;                 // xwg carries bih0
        base_dn = bhh0[16 + j];
    } else {
#pragma unroll
        for (int k = 0; k < 8; ++k) {
            wrz[k] = (v2f){ Wih1[j * 8 + k], Wih1[(8 + j) * 8 + k] };
            wnn[k] = (v2f){ Wih1[(16 + j) * 8 + k], 0.f };
            wrz[8 + k] = (v2f){ Whh1[j * 8 + k], Whh1[(8 + j) * 8 + k] };
            wnn[8 + k] = (v2f){ 0.f, Whh1[(16 + j) * 8 + k] };
        }
        base_r = bih1[j] + bhh1[j];
        base_z = bih1[8 + j] + bhh1[8 + j];
        base_in = bih1[16 + j];
        base_dn = bhh1[16 + j];
    }
    const float m0f = (layer == 0) ? 1.f : 0.f;
    __syncthreads();   // once: xwg staged

    float hown = 0.f;
    float p0 = xwg[0][j], p1 = xwg[0][8 + j], p2 = xwg[0][16 + j];
#pragma unroll 1
    for (int t = 0; t <= 128; ++t) {
        int tn = t < 127 ? t + 1 : 127;
        float q0 = xwg[tn][j], q1 = xwg[tn][8 + j], q2 = xwg[tn][16 + j];
        float vb[16];
#pragma unroll
        for (int k = 0; k < 16; ++k) vb[k] = readlanef(hown, k);
        // two independent partial chains per gate pair (depth 8)
        v2f arz0 = (v2f){ fmaf(m0f, p0, base_r), fmaf(m0f, p1, base_z) };
        v2f ann0 = (v2f){ fmaf(m0f, p2, base_in), base_dn };
        v2f arz1 = (v2f){0.f, 0.f};
        v2f ann1 = (v2f){0.f, 0.f};
#pragma unroll
        for (int k = 0; k < 8; ++k) {
            arz0 = fma2v(wrz[k], vb[k], arz0);
            ann0 = fma2v(wnn[k], vb[k], ann0);
            arz1 = fma2v(wrz[8 + k], vb[8 + k], arz1);
            ann1 = fma2v(wnn[8 + k], vb[8 + k], ann1);
        }
        v2f arz = arz0 + arz1;
        v2f ann = ann0 + ann1;
        float r = fsig(arz.x);
        float z = fsig(arz.y);
        float n = ftanh_(ann.x + r * ann.y);
        float hnew = (1.f - z) * n + z * hown;
        bool act = layer ? (t >= 1) : (t < 128);
        hown = act ? hnew : hown;
        if (tid >= 8 && tid < 16 && t >= 1) h1all[t - 1][j] = hown;
        p0 = q0; p1 = q1; p2 = q2;
    }
    __syncthreads();

    // softmax over layer-1 outputs
    float* __restrict__ outp = ws + (track ? RO : LO);
    for (int t = tid; t < 128; t += 64) {
        float vv[8];
#pragma unroll
        for (int k = 0; k < 8; ++k) vv[k] = h1all[t][k];
        float mx = vv[0];
#pragma unroll
        for (int k = 1; k < 8; ++k) mx = fmaxf(mx, vv[k]);
        float ssum = 0.f;
#pragma unroll
        for (int k = 0; k < 8; ++k) { vv[k] = __expf(vv[k] - mx); ssum += vv[k]; }
        float inv = __builtin_amdgcn_rcpf(ssum);
        size_t base = ((size_t)b * 128 + t) * 8;
        float4 o0 = make_float4(vv[0] * inv, vv[1] * inv, vv[2] * inv, vv[3] * inv);
        float4 o1 = make_float4(vv[4] * inv, vv[5] * inv, vv[6] * inv, vv[7] * inv);
        *(float4*)(outp + base) = o0;
        *(float4*)(outp + base + 4) = o1;
    }
}

// ====== K2: expert layer-1 GEMM + gate mix + batch-stat accumulation ======
__global__ __launch_bounds__(256) void k2_expert1(
    const float* __restrict__ Local, const float* __restrict__ Remote,
    const float* __restrict__ ae_w1, const float* __restrict__ ae_b1,
    float* __restrict__ ws)
{
    const int blk = blockIdx.x;
    const int track = blk >> 7;
    const int n0 = (blk & 127) * 64;
    const float* __restrict__ X = track ? Remote : Local;
    const float* __restrict__ om = ws + (track ? RO : LO);

    __shared__ __align__(16) float xsh[64 * 132];     // row stride 132
    __shared__ __align__(16) float wsh[16 * 1040];    // [h][e][130]
    __shared__ float omsh[64][8];
    __shared__ float b1sh[128];
    __shared__ float red[32];
    const int tid = threadIdx.x;

    for (int i = tid; i < 2048; i += 256) {
        int r = i >> 5, q = i & 31;
        ((float4*)&xsh[r * 132])[q] = ((const float4*)(X + (size_t)(n0 + r) * 132))[q];
    }
    for (int i4 = tid; i4 < 4096; i4 += 256) {
        float4 v = ((const float4*)ae_w1)[i4];
        int i = i4 * 4;
#pragma unroll
        for (int c = 0; c < 4; ++c) {
            int ii = i + c;
            int h = ii & 15, kk = (ii >> 4) & 127, e = ii >> 11;
            float vc = c == 0 ? v.x : c == 1 ? v.y : c == 2 ? v.z : v.w;
            wsh[h * 1040 + e * 130 + kk] = vc;
        }
    }
    for (int i = tid; i < 512; i += 256) omsh[i >> 3][i & 7] = om[(size_t)(n0 + (i >> 3)) * 8 + (i & 7)];
    for (int i = tid; i < 128; i += 256) b1sh[i] = ae_b1[i];
    if (tid < 32) red[tid] = 0.f;
    __syncthreads();

    const int hh = tid & 15, rg = tid >> 4;
    float acc[4][8];
#pragma unroll
    for (int r = 0; r < 4; ++r)
#pragma unroll
        for (int e = 0; e < 8; ++e) acc[r][e] = 0.f;

#pragma unroll 4
    for (int kq = 0; kq < 32; ++kq) {
        float4 xv[4], wv[8];
#pragma unroll
        for (int r = 0; r < 4; ++r) xv[r] = *(const float4*)&xsh[(rg * 4 + r) * 132 + kq * 4];
#pragma unroll
        for (int e = 0; e < 8; ++e) wv[e] = *(const float4*)&wsh[hh * 1040 + e * 130 + kq * 4];
#pragma unroll
        for (int r = 0; r < 4; ++r)
#pragma unroll
            for (int e = 0; e < 8; ++e) {
                float a = acc[r][e];
                a = fmaf(xv[r].x, wv[e].x, a);
                a = fmaf(xv[r].y, wv[e].y, a);
                a = fmaf(xv[r].z, wv[e].z, a);
                a = fmaf(xv[r].w, wv[e].w, a);
                acc[r][e] = a;
            }
    }

    float s = 0.f, s2 = 0.f;
    float* __restrict__ hout = ws + HBUF + (size_t)track * 131072;
#pragma unroll
    for (int r = 0; r < 4; ++r) {
        int row = rg * 4 + r;
        float hv = 0.f;
#pragma unroll
        for (int e = 0; e < 8; ++e) hv = fmaf(omsh[row][e], acc[r][e] + b1sh[e * 16 + hh], hv);
        hout[(size_t)(n0 + row) * 16 + hh] = hv;
        s += hv; s2 += hv * hv;
    }
    __syncthreads();
    atomicAdd(&red[hh], s);
    atomicAdd(&red[16 + hh], s2);
    __syncthreads();
    if (tid < 32) atomicAdd(&ws[ACC + track * 32 + tid], red[tid]);
}

// ====== K3: BN finalize + ELU + expert layer-2 + Z=ZL+ZR + xw0 precompute ======
__global__ __launch_bounds__(256) void k3_bn_mlp2(
    const float* __restrict__ ae_w2, const float* __restrict__ ae_b2,
    const float* __restrict__ ae_g, const float* __restrict__ ae_bt,
    const float* __restrict__ mWih0, const float* __restrict__ mbih0,
    float* __restrict__ ws)
{
    const int n0 = blockIdx.x * 64;
    const int tid = threadIdx.x;
    __shared__ float actsh[2][64][16];
    __shared__ float omsh[2][64][8];
    __shared__ float w2sh[2048];
    __shared__ float b2sh[128];
    __shared__ float zsh[64][17];
    __shared__ float wihsh[48][17];
    __shared__ float bihsh[48];
    __shared__ float stat[4][16];

    if (tid < 32) {
        int trk = tid >> 4, h = tid & 15;
        float s = ws[ACC + trk * 32 + h], s2 = ws[ACC + trk * 32 + 16 + h];
        float m = s * (1.f / 8192.f);
        float v = fmaxf(s2 * (1.f / 8192.f) - m * m, 0.f);
        stat[trk * 2][h] = m;
        stat[trk * 2 + 1][h] = rsqrtf(v + 1e-5f);
    }
    for (int i = tid; i < 2048; i += 256) w2sh[i] = ae_w2[i];
    for (int i = tid; i < 128; i += 256) b2sh[i] = ae_b2[i];
    for (int i = tid; i < 768; i += 256) wihsh[i >> 4][i & 15] = mWih0[i];
    if (tid < 48) bihsh[tid] = mbih0[tid];
    for (int i = tid; i < 1024; i += 256) {
        int trk = i >> 9, r = (i >> 3) & 63, e = i & 7;
        omsh[trk][r][e] = ws[(trk ? RO : LO) + (size_t)(n0 + r) * 8 + e];
    }
    __syncthreads();

    for (int i = tid; i < 2048; i += 256) {
        int trk = i >> 10, r = (i >> 4) & 63, h = i & 15;
        float v = ws[HBUF + (size_t)trk * 131072 + (size_t)(n0 + r) * 16 + h];
        float a = ae_g[h] * (v - stat[trk * 2][h]) * stat[trk * 2 + 1][h] + ae_bt[h];
        actsh[trk][r][h] = a > 0.f ? a : expm1f(a);
    }
    __syncthreads();

    for (int i = tid; i < 1024; i += 256) {
        int r = i >> 4, o = i & 15;
        float accv = 0.f;
#pragma unroll
        for (int trk = 0; trk < 2; ++trk) {
#pragma unroll
            for (int e = 0; e < 8; ++e) {
                const float* w = &w2sh[e * 256 + o];
                float t = b2sh[e * 16 + o];
#pragma unroll
                for (int h = 0; h < 16; ++h) t = fmaf(actsh[trk][r][h], w[h * 16], t);
                accv = fmaf(omsh[trk][r][e], t, accv);
            }
        }
        zsh[r][o] = accv;
    }
    __syncthreads();

    // xw0[n][48] = bih0 + Wih0 . Z[n]
    for (int i = tid; i < 3072; i += 256) {
        int r = i / 48, gr = i - r * 48;
        float a = bihsh[gr];
#pragma unroll
        for (int k = 0; k < 16; ++k) a = fmaf(zsh[r][k], wihsh[gr][k], a);
        ws[XW0 + (size_t)(n0 + r) * 48 + gr] = a;
    }
}

// ===== K4: main GRU, 1 seq/wave, skewed layers, readlane broadcast =====
// launch_bounds(64,1): no VGPR cap, 128 weight floats stay in registers.
__global__ __launch_bounds__(64, 1) void k4_maingru(
    const float* __restrict__ Whh0, const float* __restrict__ bhh0,
    const float* __restrict__ Wih1, const float* __restrict__ Whh1,
    const float* __restrict__ bih1, const float* __restrict__ bhh1,
    float* __restrict__ ws)
{
    const int tid = threadIdx.x;
    const int j = tid & 15;
    const int layer = (tid >> 4) & 1;
    const int seq = blockIdx.x;

    __shared__ __align__(16) float4 xw4[1536];   // xw0[128][48] staged
    float* xwsh = (float*)xw4;

    const float4* __restrict__ xsrc = (const float4*)(ws + XW0 + (size_t)seq * 6144);
    for (int i = tid; i < 1536; i += 64) xw4[i] = xsrc[i];

    v2f wrz[32], wnn[32];
    float base_r, base_z, base_in, base_dn;
    if (layer == 0) {
#pragma unroll
        for (int k = 0; k < 16; ++k) {
            wrz[k] = (v2f){ Whh0[j * 16 + k], Whh0[(16 + j) * 16 + k] };
            wnn[k] = (v2f){ 0.f, Whh0[(32 + j) * 16 + k] };
            wrz[16 + k] = (v2f){0.f, 0.f};
            wnn[16 + k] = (v2f){0.f, 0.f};
        }
        base_r = bhh0[j];
        base_z = bhh0[16 + j];
        base_in = 0.f;                       // xw0 carries bih0 + Wih0.z
        base_dn = bhh0[32 + j];
    } else {
#pragma unroll
        for (int k = 0; k < 16; ++k) {
            wrz[k] = (v2f){ Wih1[j * 16 + k], Wih1[(16 + j) * 16 + k] };
            wnn[k] = (v2f){ Wih1[(32 + j) * 16 + k], 0.f };
            wrz[16 + k] = (v2f){ Whh1[j * 16 + k], Whh1[(16 + j) * 16 + k] };
            wnn[16 + k] = (v2f){ 0.f, Whh1[(32 + j) * 16 + k] };
        }
        base_r = bih1[j] + bhh1[j];
        base_z = bih1[16 + j] + bhh1[16 + j];
        base_in = bih1[32 + j];
        base_dn = bhh1[32 + j];
    }
    const float m0f = (layer == 0) ? 1.f : 0.f;
    __syncthreads();   // once: xw0 staged

    float hown = 0.f;
    float p0 = xwsh[j], p1 = xwsh[16 + j], p2 = xwsh[32 + j];
#pragma unroll 1
    for (int t = 0; t <= 128; ++t) {
        int tn = (t < 127 ? t + 1 : 127) * 48;
        float q0 = xwsh[tn + j], q1 = xwsh[tn + 16 + j], q2 = xwsh[tn + 32 + j];
        float vb[32];
#pragma unroll
        for (int k = 0; k < 32; ++k) vb[k] = readlanef(hown, k);
        // two independent partial chains per gate pair (depth 16)
        v2f arz0 = (v2f){ fmaf(m0f, p0, base_r), fmaf(m0f, p1, base_z) };
        v2f ann0 = (v2f){ fmaf(m0f, p2, base_in), base_dn };
        v2f arz1 = (v2f){0.f, 0.f};
        v2f ann1 = (v2f){0.f, 0.f};
#pragma unroll
        for (int k = 0; k < 16; ++k) {
            arz0 = fma2v(wrz[k], vb[k], arz0);
            ann0 = fma2v(wnn[k], vb[k], ann0);
            arz1 = fma2v(wrz[16 + k], vb[16 + k], arz1);
            ann1 = fma2v(wnn[16 + k], vb[16 + k], ann1);
        }
        v2f arz = arz0 + arz1;
        v2f ann = ann0 + ann1;
        float r = fsig(arz.x);
        float z = fsig(arz.y);
        float n = ftanh_(ann.x + r * ann.y);
        float hnew = (1.f - z) * n + z * hown;
        bool act = layer ? (t >= 1) : (t < 128);
        hown = act ? hnew : hown;
        p0 = q0; p1 = q1; p2 = q2;
    }
    if (tid >= 16 && tid < 32) ws[ZLAST + (size_t)seq * 16 + j] = hown;
}

// ===== K5: decoder MLP fused (layer1+BN redundant per block, layer2 slice) =====
__global__ __launch_bounds__(256) void k5_dec(
    const float* __restrict__ Remote,
    const float* __restrict__ md_w1, const float* __restrict__ md_b1,
    const float* __restrict__ md_g, const float* __restrict__ md_bt,
    const float* __restrict__ md_w2, const float* __restrict__ md_b2,
    const float* __restrict__ ws, float* __restrict__ out)
{
    const int o0 = blockIdx.x * 8;
    const int tid = threadIdx.x;
    __shared__ float xsh[64][17];
    __shared__ float omsh[64][8];
    __shared__ float w1sh[2176];
    __shared__ float b1sh[128];
    __shared__ float hsh[64][17];
    __shared__ float ssum[16], ss2[16], mstat[2][16];
    __shared__ float ash[64][17];
    __shared__ float w2sh[8][16][8];
    __shared__ float b2sh[8][8];

    for (int i = tid; i < 1024; i += 256) xsh[i >> 4][i & 15] = ws[ZLAST + i];
    if (tid < 64) xsh[tid][16] = Remote[((size_t)tid * 128 + 127) * 132 + 131];
    for (int i = tid; i < 512; i += 256)
        omsh[i >> 3][i & 7] = ws[RO + ((size_t)(i >> 3) * 128 + 127) * 8 + (i & 7)];
    for (int i = tid; i < 2176; i += 256) w1sh[i] = md_w1[i];
    for (int i = tid; i < 128; i += 256) b1sh[i] = md_b1[i];
    for (int i = tid; i < 1024; i += 256) {
        int e = i >> 7, h = (i >> 3) & 15, oo = i & 7;
        w2sh[e][h][oo] = md_w2[((size_t)e * 16 + h) * 128 + o0 + oo];
    }
    if (tid < 64) b2sh[tid >> 3][tid & 7] = md_b2[(size_t)(tid >> 3) * 128 + o0 + (tid & 7)];
    if (tid < 16) { ssum[tid] = 0.f; ss2[tid] = 0.f; }
    __syncthreads();

    for (int i = tid; i < 1024; i += 256) {
        int b = i >> 4, h = i & 15;
        float accv = 0.f;
#pragma unroll
        for (int e = 0; e < 8; ++e) {
            float t = b1sh[e * 16 + h];
            const float* w = &w1sh[e * 272 + h];
#pragma unroll
            for (int i2 = 0; i2 < 17; ++i2) t = fmaf(xsh[b][i2], w[i2 * 16], t);
            accv = fmaf(omsh[b][e], t, accv);
        }
        hsh[b][h] = accv;
        atomicAdd(&ssum[h], accv);
        atomicAdd(&ss2[h], accv * accv);
    }
    __syncthreads();
    if (tid < 16) {
        float m = ssum[tid] * (1.f / 64.f);
        float v = fmaxf(ss2[tid] * (1.f / 64.f) - m * m, 0.f);
        mstat[0][tid] = m;
        mstat[1][tid] = rsqrtf(v + 1e-5f);
    }
    __syncthreads();
    for (int i = tid; i < 1024; i += 256) {
        int b = i >> 4, h = i & 15;
        float a = md_g[h] * (hsh[b][h] - mstat[0][h]) * mstat[1][h] + md_bt[h];
        ash[b][h] = a > 0.f ? a : expm1f(a);
    }
    __syncthreads();

    for (int i = tid; i < 512; i += 256) {
        int b = i >> 3, oo = i & 7;
        float accv = 0.f;
#pragma unroll
        for (int e = 0; e < 8; ++e) {
            float t = b2sh[e][oo];
#pragma unroll
            for (int h = 0; h < 16; ++h) t = fmaf(ash[b][h], w2sh[e][h][oo], t);
            accv = fmaf(omsh[b][e], t, accv);
        }
        out[(size_t)b * 128 + o0 + oo] = accv;
    }
}

extern "C" void kernel_launch(void* const* d_in, const int* in_sizes, int n_in,
                              void* d_out, int out_size, void* d_ws, size_t ws_size,
                              hipStream_t stream) {
    const float* Local  = (const float*)d_in[0];
    const float* Remote = (const float*)d_in[1];
    const float* gWih0  = (const float*)d_in[2];
    const float* gWhh0  = (const float*)d_in[3];
    const float* gbih0  = (const float*)d_in[4];
    const float* gbhh0  = (const float*)d_in[5];
    const float* gWih1  = (const float*)d_in[6];
    const float* gWhh1  = (const float*)d_in[7];
    const float* gbih1  = (const float*)d_in[8];
    const float* gbhh1  = (const float*)d_in[9];
    const float* mWih0  = (const float*)d_in[10];
    const float* mWhh0  = (const float*)d_in[11];
    const float* mbih0  = (const float*)d_in[12];
    const float* mbhh0  = (const float*)d_in[13];
    const float* mWih1  = (const float*)d_in[14];
    const float* mWhh1  = (const float*)d_in[15];
    const float* mbih1  = (const float*)d_in[16];
    const float* mbhh1  = (const float*)d_in[17];
    const float* ae_w1  = (const float*)d_in[18];
    const float* ae_b1  = (const float*)d_in[19];
    const float* ae_w2  = (const float*)d_in[20];
    const float* ae_b2  = (const float*)d_in[21];
    const float* ae_g   = (const float*)d_in[22];
    const float* ae_bt  = (const float*)d_in[23];
    const float* md_w1  = (const float*)d_in[24];
    const float* md_b1  = (const float*)d_in[25];
    const float* md_w2  = (const float*)d_in[26];
    const float* md_b2  = (const float*)d_in[27];
    const float* md_g   = (const float*)d_in[28];
    const float* md_bt  = (const float*)d_in[29];
    float* ws  = (float*)d_ws;
    float* out = (float*)d_out;

    k1_gate<<<128, 64, 0, stream>>>(Local, Remote, gWih0, gWhh0, gbih0, gbhh0,
                                    gWih1, gWhh1, gbih1, gbhh1, ws);
    k2_expert1<<<256, 256, 0, stream>>>(Local, Remote, ae_w1, ae_b1, ws);
    k3_bn_mlp2<<<128, 256, 0, stream>>>(ae_w2, ae_b2, ae_g, ae_bt, mWih0, mbih0, ws);
    k4_maingru<<<64, 64, 0, stream>>>(mWhh0, mbhh0, mWih1, mWhh1, mbih1, mbhh1, ws);
    k5_dec<<<16, 256, 0, stream>>>(Remote, md_w1, md_b1, md_g, md_bt,
                                   md_w2, md_b2, ws, out);
}

// Round 6
// 246.625 us; speedup vs baseline: 1.0740x; 1.0050x over previous
//
#include <hip/hip_runtime.h>
#include <cstdint>
#include <cstddef>

#define DEV __device__ __forceinline__

DEV float fsig(float x)  { return __builtin_amdgcn_rcpf(1.0f + __expf(-x)); }
DEV float ftanh_(float x){ return 1.0f - 2.0f * __builtin_amdgcn_rcpf(1.0f + __expf(2.0f * x)); }
DEV float readlanef(float v, int l) {
    return __uint_as_float(__builtin_amdgcn_readlane(__float_as_uint(v), l));
}

// ---------------- ws layout (float offsets) ----------------
constexpr size_t ACC   = 0;                 // 64  (2 tracks x (16 sum + 16 sumsq))
constexpr size_t LO    = 128;               // 65536  Lo[64][128][8]
constexpr size_t RO    = LO + 65536;        // 65536  Ro[64][128][8]
constexpr size_t HBUF  = RO + 65536;        // 262144 h[track][8192][16]
constexpr size_t ZLAST = HBUF + 262144;     // 1024   zlast[64][16]

// ===== K1: gate GRU, 1 seq/wave, skewed layers, readlane broadcast =====
// Branch-free weight init (SROA-friendly): 48 weight floats/lane.
__global__ __launch_bounds__(64, 1) void k1_gate(
    const float* __restrict__ Local, const float* __restrict__ Remote,
    const float* __restrict__ Wih0, const float* __restrict__ Whh0,
    const float* __restrict__ bih0, const float* __restrict__ bhh0,
    const float* __restrict__ Wih1, const float* __restrict__ Whh1,
    const float* __restrict__ bih1, const float* __restrict__ bhh1,
    float* __restrict__ ws)
{
    const int tid = threadIdx.x;
    const int j = tid & 7;
    const int layer = (tid >> 3) & 1;
    const int blk = blockIdx.x;
    const int track = blk >> 6;
    const int b = blk & 63;
    if (blk == 0) ws[ACC + tid] = 0.f;

    __shared__ float xwg[128][24];     // precomputed bih0 + Wih0 . x(t)
    __shared__ float h1all[128][9];

    const float* __restrict__ src = track ? Remote : Local;
    for (int t = tid; t < 128; t += 64) {
        const float* p = src + ((size_t)b * 128 + t) * 132 + 128;
        float x0 = p[0], x1 = p[1], x2 = p[2];
#pragma unroll
        for (int u = 0; u < 24; ++u) {
            float a = bih0[u];
            a = fmaf(Wih0[u * 3 + 0], x0, a);
            a = fmaf(Wih0[u * 3 + 1], x1, a);
            a = fmaf(Wih0[u * 3 + 2], x2, a);
            xwg[t][u] = a;
        }
    }

    // straight-line weight init: no control flow over the aggregate
    const float* __restrict__ Wlo = layer ? Wih1 : Whh0;
    const float mhi = layer ? 1.f : 0.f;
    const float m0f = layer ? 0.f : 1.f;
    float wr[16], wz[16], wc[16];
#pragma unroll
    for (int k = 0; k < 8; ++k) {
        wr[k] = Wlo[j * 8 + k];
        wz[k] = Wlo[(8 + j) * 8 + k];
        wc[k] = Wlo[(16 + j) * 8 + k];
        wr[8 + k] = mhi * Whh1[j * 8 + k];
        wz[8 + k] = mhi * Whh1[(8 + j) * 8 + k];
        wc[8 + k] = mhi * Whh1[(16 + j) * 8 + k];
    }
    const float base_r  = layer ? (bih1[j] + bhh1[j])         : bhh0[j];
    const float base_z  = layer ? (bih1[8 + j] + bhh1[8 + j]) : bhh0[8 + j];
    const float base_in = layer ? bih1[16 + j]                : 0.f;
    const float base_dn = layer ? bhh1[16 + j]                : bhh0[16 + j];
    __syncthreads();   // once: xwg staged

    float hown = 0.f;
    float p0 = xwg[0][j], p1 = xwg[0][8 + j], p2 = xwg[0][16 + j];
#pragma unroll 1
    for (int t = 0; t <= 128; ++t) {
        int tn = t < 127 ? t + 1 : 127;
        float q0 = xwg[tn][j], q1 = xwg[tn][8 + j], q2 = xwg[tn][16 + j];
        float vb[16];
#pragma unroll
        for (int k = 0; k < 16; ++k) vb[k] = readlanef(hown, k);
        float ar_a = fmaf(m0f, p0, base_r), ar_b = 0.f;
        float az_a = fmaf(m0f, p1, base_z), az_b = 0.f;
        float ac_lo = 0.f, ac_hi = 0.f;
#pragma unroll
        for (int k = 0; k < 8; ++k) {
            ar_a  = fmaf(wr[k], vb[k], ar_a);
            az_a  = fmaf(wz[k], vb[k], az_a);
            ac_lo = fmaf(wc[k], vb[k], ac_lo);
            ar_b  = fmaf(wr[8 + k], vb[8 + k], ar_b);
            az_b  = fmaf(wz[8 + k], vb[8 + k], az_b);
            ac_hi = fmaf(wc[8 + k], vb[8 + k], ac_hi);
        }
        float r = fsig(ar_a + ar_b);
        float z = fsig(az_a + az_b);
        float tin = base_in + ac_lo;
        float in_ = layer ? tin : p2;
        float dn  = base_dn + (layer ? ac_hi : ac_lo);
        float n = ftanh_(in_ + r * dn);
        float hnew = (1.f - z) * n + z * hown;
        bool act = layer ? (t >= 1) : (t < 128);
        hown = act ? hnew : hown;
        if (tid >= 8 && tid < 16 && t >= 1) h1all[t - 1][j] = hown;
        p0 = q0; p1 = q1; p2 = q2;
    }
    __syncthreads();

    // softmax over layer-1 outputs
    float* __restrict__ outp = ws + (track ? RO : LO);
    for (int t = tid; t < 128; t += 64) {
        float vv[8];
#pragma unroll
        for (int k = 0; k < 8; ++k) vv[k] = h1all[t][k];
        float mx = vv[0];
#pragma unroll
        for (int k = 1; k < 8; ++k) mx = fmaxf(mx, vv[k]);
        float ssum = 0.f;
#pragma unroll
        for (int k = 0; k < 8; ++k) { vv[k] = __expf(vv[k] - mx); ssum += vv[k]; }
        float inv = __builtin_amdgcn_rcpf(ssum);
        size_t base = ((size_t)b * 128 + t) * 8;
        float4 o0 = make_float4(vv[0] * inv, vv[1] * inv, vv[2] * inv, vv[3] * inv);
        float4 o1 = make_float4(vv[4] * inv, vv[5] * inv, vv[6] * inv, vv[7] * inv);
        *(float4*)(outp + base) = o0;
        *(float4*)(outp + base + 4) = o1;
    }
}

// ====== K2: expert layer-1 GEMM + gate mix + batch-stat accumulation ======
__global__ __launch_bounds__(256) void k2_expert1(
    const float* __restrict__ Local, const float* __restrict__ Remote,
    const float* __restrict__ ae_w1, const float* __restrict__ ae_b1,
    float* __restrict__ ws)
{
    const int blk = blockIdx.x;
    const int track = blk >> 7;
    const int n0 = (blk & 127) * 64;
    const float* __restrict__ X = track ? Remote : Local;
    const float* __restrict__ om = ws + (track ? RO : LO);

    __shared__ __align__(16) float xsh[64 * 132];     // row stride 132
    __shared__ __align__(16) float wsh[16 * 1040];    // [h][e][130]
    __shared__ float omsh[64][8];
    __shared__ float b1sh[128];
    __shared__ float red[32];
    const int tid = threadIdx.x;

    for (int i = tid; i < 2048; i += 256) {
        int r = i >> 5, q = i & 31;
        ((float4*)&xsh[r * 132])[q] = ((const float4*)(X + (size_t)(n0 + r) * 132))[q];
    }
    for (int i4 = tid; i4 < 4096; i4 += 256) {
        float4 v = ((const float4*)ae_w1)[i4];
        int i = i4 * 4;
#pragma unroll
        for (int c = 0; c < 4; ++c) {
            int ii = i + c;
            int h = ii & 15, kk = (ii >> 4) & 127, e = ii >> 11;
            float vc = c == 0 ? v.x : c == 1 ? v.y : c == 2 ? v.z : v.w;
            wsh[h * 1040 + e * 130 + kk] = vc;
        }
    }
    for (int i = tid; i < 512; i += 256) omsh[i >> 3][i & 7] = om[(size_t)(n0 + (i >> 3)) * 8 + (i & 7)];
    for (int i = tid; i < 128; i += 256) b1sh[i] = ae_b1[i];
    if (tid < 32) red[tid] = 0.f;
    __syncthreads();

    const int hh = tid & 15, rg = tid >> 4;
    float acc[4][8];
#pragma unroll
    for (int r = 0; r < 4; ++r)
#pragma unroll
        for (int e = 0; e < 8; ++e) acc[r][e] = 0.f;

#pragma unroll 4
    for (int kq = 0; kq < 32; ++kq) {
        float4 xv[4], wv[8];
#pragma unroll
        for (int r = 0; r < 4; ++r) xv[r] = *(const float4*)&xsh[(rg * 4 + r) * 132 + kq * 4];
#pragma unroll
        for (int e = 0; e < 8; ++e) wv[e] = *(const float4*)&wsh[hh * 1040 + e * 130 + kq * 4];
#pragma unroll
        for (int r = 0; r < 4; ++r)
#pragma unroll
            for (int e = 0; e < 8; ++e) {
                float a = acc[r][e];
                a = fmaf(xv[r].x, wv[e].x, a);
                a = fmaf(xv[r].y, wv[e].y, a);
                a = fmaf(xv[r].z, wv[e].z, a);
                a = fmaf(xv[r].w, wv[e].w, a);
                acc[r][e] = a;
            }
    }

    float s = 0.f, s2 = 0.f;
    float* __restrict__ hout = ws + HBUF + (size_t)track * 131072;
#pragma unroll
    for (int r = 0; r < 4; ++r) {
        int row = rg * 4 + r;
        float hv = 0.f;
#pragma unroll
        for (int e = 0; e < 8; ++e) hv = fmaf(omsh[row][e], acc[r][e] + b1sh[e * 16 + hh], hv);
        hout[(size_t)(n0 + row) * 16 + hh] = hv;
        s += hv; s2 += hv * hv;
    }
    __syncthreads();
    atomicAdd(&red[hh], s);
    atomicAdd(&red[16 + hh], s2);
    __syncthreads();
    if (tid < 32) atomicAdd(&ws[ACC + track * 32 + tid], red[tid]);
}

// ===== K34: fused BN+ELU+MLP2+xw0 (per-sequence, phase A, 256 thr) then
//            main GRU recurrence (phase B, wave 0 only). 64 blocks. =====
__global__ __launch_bounds__(256, 1) void k34_fused(
    const float* __restrict__ ae_w2, const float* __restrict__ ae_b2,
    const float* __restrict__ ae_g, const float* __restrict__ ae_bt,
    const float* __restrict__ mWih0, const float* __restrict__ mbih0,
    const float* __restrict__ Whh0, const float* __restrict__ bhh0,
    const float* __restrict__ Wih1, const float* __restrict__ Whh1,
    const float* __restrict__ bih1, const float* __restrict__ bhh1,
    float* __restrict__ ws)
{
    const int s = blockIdx.x;           // sequence 0..63
    const int tid = threadIdx.x;

    __shared__ float stat[4][16];
    __shared__ float omsh[2][128][8];
    __shared__ float w2sh[2048];
    __shared__ float b2sh[128];
    __shared__ float actsh[2][128][16];
    __shared__ float zsh[128][17];
    __shared__ float wihsh[48][17];
    __shared__ float bihsh[48];
    __shared__ float xwsh[128 * 48];

    // ---- phase A ----
    if (tid < 32) {
        int trk = tid >> 4, h = tid & 15;
        float sm = ws[ACC + trk * 32 + h], s2 = ws[ACC + trk * 32 + 16 + h];
        float m = sm * (1.f / 8192.f);
        float v = fmaxf(s2 * (1.f / 8192.f) - m * m, 0.f);
        stat[trk * 2][h] = m;
        stat[trk * 2 + 1][h] = rsqrtf(v + 1e-5f);
    }
    for (int i = tid; i < 2048; i += 256) w2sh[i] = ae_w2[i];
    for (int i = tid; i < 128; i += 256) b2sh[i] = ae_b2[i];
    for (int i = tid; i < 768; i += 256) wihsh[i >> 4][i & 15] = mWih0[i];
    if (tid < 48) bihsh[tid] = mbih0[tid];
    for (int i = tid; i < 2048; i += 256) {
        int trk = i >> 10, r = (i >> 3) & 127, e = i & 7;
        omsh[trk][r][e] = ws[(trk ? RO : LO) + ((size_t)s * 128 + r) * 8 + e];
    }
    __syncthreads();

    for (int i = tid; i < 4096; i += 256) {
        int trk = i >> 11, r = (i >> 4) & 127, h = i & 15;
        float v = ws[HBUF + (size_t)trk * 131072 + ((size_t)s * 128 + r) * 16 + h];
        float a = ae_g[h] * (v - stat[trk * 2][h]) * stat[trk * 2 + 1][h] + ae_bt[h];
        actsh[trk][r][h] = a > 0.f ? a : expm1f(a);
    }
    __syncthreads();

    for (int i = tid; i < 2048; i += 256) {
        int r = i >> 4, o = i & 15;
        float accv = 0.f;
#pragma unroll
        for (int trk = 0; trk < 2; ++trk) {
#pragma unroll
            for (int e = 0; e < 8; ++e) {
                const float* w = &w2sh[e * 256 + o];
                float t = b2sh[e * 16 + o];
#pragma unroll
                for (int h = 0; h < 16; ++h) t = fmaf(actsh[trk][r][h], w[h * 16], t);
                accv = fmaf(omsh[trk][r][e], t, accv);
            }
        }
        zsh[r][o] = accv;
    }
    __syncthreads();

    for (int i = tid; i < 6144; i += 256) {
        int r = i / 48, g = i - r * 48;
        float a = bihsh[g];
#pragma unroll
        for (int k = 0; k < 16; ++k) a = fmaf(zsh[r][k], wihsh[g][k], a);
        xwsh[r * 48 + g] = a;
    }
    __syncthreads();

    // ---- phase B: recurrence, wave 0 only ----
    if (tid >= 64) return;

    const int j = tid & 15;
    const int layer = (tid >> 4) & 1;

    const float* __restrict__ Wlo = layer ? Wih1 : Whh0;
    const float mhi = layer ? 1.f : 0.f;
    const float m0f = layer ? 0.f : 1.f;
    float wr[32], wz[32], wc[32];
#pragma unroll
    for (int k = 0; k < 16; ++k) {
        wr[k] = Wlo[j * 16 + k];
        wz[k] = Wlo[(16 + j) * 16 + k];
        wc[k] = Wlo[(32 + j) * 16 + k];
        wr[16 + k] = mhi * Whh1[j * 16 + k];
        wz[16 + k] = mhi * Whh1[(16 + j) * 16 + k];
        wc[16 + k] = mhi * Whh1[(32 + j) * 16 + k];
    }
    const float base_r  = layer ? (bih1[j] + bhh1[j])           : bhh0[j];
    const float base_z  = layer ? (bih1[16 + j] + bhh1[16 + j]) : bhh0[16 + j];
    const float base_in = layer ? bih1[32 + j]                  : 0.f;
    const float base_dn = layer ? bhh1[32 + j]                  : bhh0[32 + j];

    float hown = 0.f;
    float p0 = xwsh[j], p1 = xwsh[16 + j], p2 = xwsh[32 + j];
#pragma unroll 1
    for (int t = 0; t <= 128; ++t) {
        int tn = (t < 127 ? t + 1 : 127) * 48;
        float q0 = xwsh[tn + j], q1 = xwsh[tn + 16 + j], q2 = xwsh[tn + 32 + j];
        float vb[32];
#pragma unroll
        for (int k = 0; k < 32; ++k) vb[k] = readlanef(hown, k);
        float ar_a = fmaf(m0f, p0, base_r), ar_b = 0.f;
        float az_a = fmaf(m0f, p1, base_z), az_b = 0.f;
        float ac_lo = 0.f, ac_hi = 0.f;
#pragma unroll
        for (int k = 0; k < 16; ++k) {
            ar_a  = fmaf(wr[k], vb[k], ar_a);
            az_a  = fmaf(wz[k], vb[k], az_a);
            ac_lo = fmaf(wc[k], vb[k], ac_lo);
            ar_b  = fmaf(wr[16 + k], vb[16 + k], ar_b);
            az_b  = fmaf(wz[16 + k], vb[16 + k], az_b);
            ac_hi = fmaf(wc[16 + k], vb[16 + k], ac_hi);
        }
        float r = fsig(ar_a + ar_b);
        float z = fsig(az_a + az_b);
        float tin = base_in + ac_lo;
        float in_ = layer ? tin : p2;
        float dn  = base_dn + (layer ? ac_hi : ac_lo);
        float n = ftanh_(in_ + r * dn);
        float hnew = (1.f - z) * n + z * hown;
        bool act = layer ? (t >= 1) : (t < 128);
        hown = act ? hnew : hown;
        p0 = q0; p1 = q1; p2 = q2;
    }
    if (tid >= 16 && tid < 32) ws[ZLAST + (size_t)s * 16 + j] = hown;
}

// ===== K5: decoder MLP fused (layer1+BN redundant per block, layer2 slice) =====
__global__ __launch_bounds__(256) void k5_dec(
    const float* __restrict__ Remote,
    const float* __restrict__ md_w1, const float* __restrict__ md_b1,
    const float* __restrict__ md_g, const float* __restrict__ md_bt,
    const float* __restrict__ md_w2, const float* __restrict__ md_b2,
    const float* __restrict__ ws, float* __restrict__ out)
{
    const int o0 = blockIdx.x * 8;
    const int tid = threadIdx.x;
    __shared__ float xsh[64][17];
    __shared__ float omsh[64][8];
    __shared__ float w1sh[2176];
    __shared__ float b1sh[128];
    __shared__ float hsh[64][17];
    __shared__ float ssum[16], ss2[16], mstat[2][16];
    __shared__ float ash[64][17];
    __shared__ float w2sh[8][16][8];
    __shared__ float b2sh[8][8];

    for (int i = tid; i < 1024; i += 256) xsh[i >> 4][i & 15] = ws[ZLAST + i];
    if (tid < 64) xsh[tid][16] = Remote[((size_t)tid * 128 + 127) * 132 + 131];
    for (int i = tid; i < 512; i += 256)
        omsh[i >> 3][i & 7] = ws[RO + ((size_t)(i >> 3) * 128 + 127) * 8 + (i & 7)];
    for (int i = tid; i < 2176; i += 256) w1sh[i] = md_w1[i];
    for (int i = tid; i < 128; i += 256) b1sh[i] = md_b1[i];
    for (int i = tid; i < 1024; i += 256) {
        int e = i >> 7, h = (i >> 3) & 15, oo = i & 7;
        w2sh[e][h][oo] = md_w2[((size_t)e * 16 + h) * 128 + o0 + oo];
    }
    if (tid < 64) b2sh[tid >> 3][tid & 7] = md_b2[(size_t)(tid >> 3) * 128 + o0 + (tid & 7)];
    if (tid < 16) { ssum[tid] = 0.f; ss2[tid] = 0.f; }
    __syncthreads();

    for (int i = tid; i < 1024; i += 256) {
        int b = i >> 4, h = i & 15;
        float accv = 0.f;
#pragma unroll
        for (int e = 0; e < 8; ++e) {
            float t = b1sh[e * 16 + h];
            const float* w = &w1sh[e * 272 + h];
#pragma unroll
            for (int i2 = 0; i2 < 17; ++i2) t = fmaf(xsh[b][i2], w[i2 * 16], t);
            accv = fmaf(omsh[b][e], t, accv);
        }
        hsh[b][h] = accv;
        atomicAdd(&ssum[h], accv);
        atomicAdd(&ss2[h], accv * accv);
    }
    __syncthreads();
    if (tid < 16) {
        float m = ssum[tid] * (1.f / 64.f);
        float v = fmaxf(ss2[tid] * (1.f / 64.f) - m * m, 0.f);
        mstat[0][tid] = m;
        mstat[1][tid] = rsqrtf(v + 1e-5f);
    }
    __syncthreads();
    for (int i = tid; i < 1024; i += 256) {
        int b = i >> 4, h = i & 15;
        float a = md_g[h] * (hsh[b][h] - mstat[0][h]) * mstat[1][h] + md_bt[h];
        ash[b][h] = a > 0.f ? a : expm1f(a);
    }
    __syncthreads();

    for (int i = tid; i < 512; i += 256) {
        int b = i >> 3, oo = i & 7;
        float accv = 0.f;
#pragma unroll
        for (int e = 0; e < 8; ++e) {
            float t = b2sh[e][oo];
#pragma unroll
            for (int h = 0; h < 16; ++h) t = fmaf(ash[b][h], w2sh[e][h][oo], t);
            accv = fmaf(omsh[b][e], t, accv);
        }
        out[(size_t)b * 128 + o0 + oo] = accv;
    }
}

extern "C" void kernel_launch(void* const* d_in, const int* in_sizes, int n_in,
                              void* d_out, int out_size, void* d_ws, size_t ws_size,
                              hipStream_t stream) {
    const float* Local  = (const float*)d_in[0];
    const float* Remote = (const float*)d_in[1];
    const float* gWih0  = (const float*)d_in[2];
    const float* gWhh0  = (const float*)d_in[3];
    const float* gbih0  = (const float*)d_in[4];
    const float* gbhh0  = (const float*)d_in[5];
    const float* gWih1  = (const float*)d_in[6];
    const float* gWhh1  = (const float*)d_in[7];
    const float* gbih1  = (const float*)d_in[8];
    const float* gbhh1  = (const float*)d_in[9];
    const float* mWih0  = (const float*)d_in[10];
    const float* mWhh0  = (const float*)d_in[11];
    const float* mbih0  = (const float*)d_in[12];
    const float* mbhh0  = (const float*)d_in[13];
    const float* mWih1  = (const float*)d_in[14];
    const float* mWhh1  = (const float*)d_in[15];
    const float* mbih1  = (const float*)d_in[16];
    const float* mbhh1  = (const float*)d_in[17];
    const float* ae_w1  = (const float*)d_in[18];
    const float* ae_b1  = (const float*)d_in[19];
    const float* ae_w2  = (const float*)d_in[20];
    const float* ae_b2  = (const float*)d_in[21];
    const float* ae_g   = (const float*)d_in[22];
    const float* ae_bt  = (const float*)d_in[23];
    const float* md_w1  = (const float*)d_in[24];
    const float* md_b1  = (const float*)d_in[25];
    const float* md_w2  = (const float*)d_in[26];
    const float* md_b2  = (const float*)d_in[27];
    const float* md_g   = (const float*)d_in[28];
    const float* md_bt  = (const float*)d_in[29];
    float* ws  = (float*)d_ws;
    float* out = (float*)d_out;

    k1_gate<<<128, 64, 0, stream>>>(Local, Remote, gWih0, gWhh0, gbih0, gbhh0,
                                    gWih1, gWhh1, gbih1, gbhh1, ws);
    k2_expert1<<<256, 256, 0, stream>>>(Local, Remote, ae_w1, ae_b1, ws);
    k34_fused<<<64, 256, 0, stream>>>(ae_w2, ae_b2, ae_g, ae_bt, mWih0, mbih0,
                                      mWhh0, mbhh0, mWih1, mWhh1, mbih1, mbhh1, ws);
    k5_dec<<<16, 256, 0, stream>>>(Remote, md_w1, md_b1, md_g, md_bt,
                                   md_w2, md_b2, ws, out);
}